// Round 5
// baseline (131.822 us; speedup 1.0000x reference)
//
#include <hip/hip_runtime.h>
#include <hip/hip_bf16.h>

#define S 128
#define DFEAT 150528
#define RSB 602112u               // row stride bytes
#define NCHUNK 4704               // DFEAT / 32
#define GRID 256

typedef short short8 __attribute__((ext_vector_type(8)));
typedef float f32x4 __attribute__((ext_vector_type(4)));

__device__ __forceinline__ short bf1(float x) {
    union { __hip_bfloat16 h; short s; } u;
    u.h = __float2bfloat16(x);
    return u.s;
}
__device__ __forceinline__ short8 cvt8(float4 a, float4 b) {
    short8 r;
    r[0] = bf1(a.x); r[1] = bf1(a.y); r[2] = bf1(a.z); r[3] = bf1(a.w);
    r[4] = bf1(b.x); r[5] = bf1(b.y); r[6] = bf1(b.z); r[7] = bf1(b.w);
    return r;
}
__device__ __forceinline__ float ssq4(float4 v) {
    return v.x*v.x + v.y*v.y + v.z*v.z + v.w*v.w;
}

// K1: 128x128 Gram, K-split over 256 blocks, barrier-free main loop.
// Each lane loads its MFMA fragment straight from global (L1/L2 absorb the
// 4x intra-block reuse). Chunk order rotated per block to de-phase DRAM
// channels. Per block: partial tile -> padded LDS -> 255 diagonal sums.
// A = clip2 (matrix rows, x), B = clip1 (matrix cols, y).
__global__ __launch_bounds__(1024, 4) void k1_gram(
    const char* __restrict__ A, const char* __restrict__ B,
    float* __restrict__ diag, float* __restrict__ sqBuf)
{
    __shared__ float ldsF[64 * 129];   // epilogue only

    const int t = threadIdx.x, g = blockIdx.x;
    const int w = t >> 6, l = t & 63;
    const int wrow = w >> 2, wcol = w & 3;   // 4x4 wave grid, 32x32 out each
    const int fr = l & 15, grp = l >> 4;

    // fragment source offsets (bytes); lane covers k = c*32 + grp*8 .. +7
    const unsigned aOff0 = (unsigned)(wrow * 32 + fr) * RSB + grp * 32u;
    const unsigned aOff1 = aOff0 + 16u * RSB;
    const unsigned bOff0 = (unsigned)(wcol * 32 + fr) * RSB + grp * 32u;
    const unsigned bOff1 = bOff0 + 16u * RSB;

    const bool doSqA = (wcol == 0), doSqB = (wrow == 0);

    f32x4 acc00 = {0,0,0,0}, acc01 = {0,0,0,0}, acc10 = {0,0,0,0}, acc11 = {0,0,0,0};
    float sqa0 = 0.f, sqa1 = 0.f, sqb0 = 0.f, sqb1 = 0.f;

    float4 pa[2][4], pb[2][4];   // ping-pong, constant-indexed only

#define LOADQ(BUF, CB) do {                                        \
    pa[BUF][0] = *(const float4*)(A + aOff0 + (CB));               \
    pa[BUF][1] = *(const float4*)(A + aOff0 + (CB) + 16u);         \
    pa[BUF][2] = *(const float4*)(A + aOff1 + (CB));               \
    pa[BUF][3] = *(const float4*)(A + aOff1 + (CB) + 16u);         \
    pb[BUF][0] = *(const float4*)(B + bOff0 + (CB));               \
    pb[BUF][1] = *(const float4*)(B + bOff0 + (CB) + 16u);         \
    pb[BUF][2] = *(const float4*)(B + bOff1 + (CB));               \
    pb[BUF][3] = *(const float4*)(B + bOff1 + (CB) + 16u);         \
} while (0)

#define COMPUTE(BUF) do {                                          \
    short8 fA0 = cvt8(pa[BUF][0], pa[BUF][1]);                     \
    short8 fA1 = cvt8(pa[BUF][2], pa[BUF][3]);                     \
    short8 fB0 = cvt8(pb[BUF][0], pb[BUF][1]);                     \
    short8 fB1 = cvt8(pb[BUF][2], pb[BUF][3]);                     \
    if (doSqA) {                                                   \
        sqa0 += ssq4(pa[BUF][0]) + ssq4(pa[BUF][1]);               \
        sqa1 += ssq4(pa[BUF][2]) + ssq4(pa[BUF][3]);               \
    }                                                              \
    if (doSqB) {                                                   \
        sqb0 += ssq4(pb[BUF][0]) + ssq4(pb[BUF][1]);               \
        sqb1 += ssq4(pb[BUF][2]) + ssq4(pb[BUF][3]);               \
    }                                                              \
    acc00 = __builtin_amdgcn_mfma_f32_16x16x32_bf16(fA0, fB0, acc00, 0, 0, 0); \
    acc01 = __builtin_amdgcn_mfma_f32_16x16x32_bf16(fA0, fB1, acc01, 0, 0, 0); \
    acc10 = __builtin_amdgcn_mfma_f32_16x16x32_bf16(fA1, fB0, acc10, 0, 0, 0); \
    acc11 = __builtin_amdgcn_mfma_f32_16x16x32_bf16(fA1, fB1, acc11, 0, 0, 0); \
} while (0)

    // chunk schedule: step k -> chunk c(k) = k*256 + ((g+k)&255).
    // Perfect partition over blocks; per-block DRAM phase rotates every step.
    int k = 0;
    unsigned c0 = (unsigned)(g & 255);
    LOADQ(0, c0 * 128u);
    for (;;) {
        int k1i = k + 1;
        unsigned c1 = (unsigned)k1i * 256u + (unsigned)((g + k1i) & 255);
        bool m1 = c1 < NCHUNK;
        if (m1) LOADQ(1, c1 * 128u);
        COMPUTE(0);
        if (!m1) break;
        int k2i = k + 2;
        unsigned c2 = (unsigned)k2i * 256u + (unsigned)((g + k2i) & 255);
        bool m2 = c2 < NCHUNK;
        if (m2) LOADQ(0, c2 * 128u);
        COMPUTE(1);
        if (!m2) break;
        k = k2i;
    }
#undef LOADQ
#undef COMPUTE

    // ---- epilogue: two 64-row passes through padded LDS, stride 129 ----
    // C/D layout: col = lane&15, row = (lane>>4)*4 + reg
    float dsum = 0.f;
    const int del = t - 127;
#define STORE_ACC(ACC, TM, TN) do {                                \
    int row0 = wrow * 32 + (TM) * 16 + grp * 4 - h * 64;           \
    int colX = wcol * 32 + (TN) * 16 + fr;                         \
    ldsF[(row0 + 0) * 129 + colX] = ACC[0];                        \
    ldsF[(row0 + 1) * 129 + colX] = ACC[1];                        \
    ldsF[(row0 + 2) * 129 + colX] = ACC[2];                        \
    ldsF[(row0 + 3) * 129 + colX] = ACC[3];                        \
} while (0)
    for (int h = 0; h < 2; h++) {
        if (h) __syncthreads();            // half-0 reads done before overwrite
        if ((wrow >> 1) == h) {
            STORE_ACC(acc00, 0, 0); STORE_ACC(acc01, 0, 1);
            STORE_ACC(acc10, 1, 0); STORE_ACC(acc11, 1, 1);
        }
        __syncthreads();
        if (t < 255) {
            int rlo = del < 0 ? -del : 0;
            int rhi = del < 0 ? 127 : 127 - del;   // inclusive
            if (rlo < h * 64) rlo = h * 64;
            if (rhi > h * 64 + 63) rhi = h * 64 + 63;
            for (int r = rlo; r <= rhi; r++)
                dsum += ldsF[(r - h * 64) * 129 + r + del];  // consecutive banks
        }
    }
#undef STORE_ACC
    if (t < 255) atomicAdd(&diag[t], dsum);

    // ---- row sum-of-squares: reduce over grp lanes, atomic per row ----
    if (doSqA) {
        sqa0 += __shfl_xor(sqa0, 16); sqa0 += __shfl_xor(sqa0, 32);
        sqa1 += __shfl_xor(sqa1, 16); sqa1 += __shfl_xor(sqa1, 32);
        if (l < 16) {
            atomicAdd(&sqBuf[wrow * 32 + fr], sqa0);
            atomicAdd(&sqBuf[wrow * 32 + 16 + fr], sqa1);
        }
    }
    if (doSqB) {
        sqb0 += __shfl_xor(sqb0, 16); sqb0 += __shfl_xor(sqb0, 32);
        sqb1 += __shfl_xor(sqb1, 16); sqb1 += __shfl_xor(sqb1, 32);
        if (l < 16) {
            atomicAdd(&sqBuf[128 + wcol * 32 + fr], sqb0);
            atomicAdd(&sqBuf[128 + wcol * 32 + 16 + fr], sqb1);
        }
    }
}

// K3: combine diag gram sums with sq-norm terms -> 129 outputs.
__global__ void k3_out(const float* __restrict__ sqBuf,
                       const float* __restrict__ diag,
                       float* __restrict__ out)
{
    int o = threadIdx.x;
    if (o >= 129) return;
    int d   = o - 64;
    int ad  = d < 0 ? -d : d;
    int cnt = 128 - ad;
    int i0  = d < 0 ? -d : 0;
    float sq = 0.f;
    for (int tt = 0; tt < cnt; tt++) {
        int i = i0 + tt;
        sq += sqBuf[i] + sqBuf[128 + i + d];
    }
    float gv = diag[63 + o];
    out[o] = -((sq - 2.f * gv) * (1.0f / (float)DFEAT)) * 1e13f / (float)cnt;
}

extern "C" void kernel_launch(void* const* d_in, const int* in_sizes, int n_in,
                              void* d_out, int out_size, void* d_ws, size_t ws_size,
                              hipStream_t stream) {
    const char* clip1 = (const char*)d_in[0];  // b: matrix cols (y)
    const char* clip2 = (const char*)d_in[1];  // a: matrix rows (x)
    float* out = (float*)d_out;

    float* sqBuf = (float*)d_ws;          // 256 floats
    float* diag  = sqBuf + 256;           // 255 floats

    hipMemsetAsync(d_ws, 0, 4096, stream);
    k1_gram<<<dim3(GRID), dim3(1024), 0, stream>>>(clip2, clip1, diag, sqBuf);
    k3_out<<<dim3(1), dim3(256), 0, stream>>>(sqBuf, diag, out);
}

// Round 7
// 58.502 us; speedup vs baseline: 2.2533x; 2.2533x over previous
//
#include <hip/hip_runtime.h>

#define S 128
#define DFEAT 150528
#define NC_TOT 2352            // DFEAT/64 K-chunks (64 elements each)
#define TILE_B 8192            // one chunk tile: 128 rows x 64 fp8 bytes

typedef float f32x4 __attribute__((ext_vector_type(4)));

__device__ __forceinline__ unsigned fp8x4(float4 v) {
    int r = 0;
    r = __builtin_amdgcn_cvt_pk_fp8_f32(v.x, v.y, r, false);  // bytes 0,1
    r = __builtin_amdgcn_cvt_pk_fp8_f32(v.z, v.w, r, true);   // bytes 2,3
    return (unsigned)r;
}

__device__ __forceinline__ void gload16(const void* g, void* l) {
    __builtin_amdgcn_global_load_lds(
        (const __attribute__((address_space(1))) unsigned int*)g,
        (__attribute__((address_space(3))) unsigned int*)(void*)l,
        16, 0, 0);
}

// Pass 1: stream one contiguous ~150KB slab per block (m13 pattern), fp32
// sq-norms (exact), fp8-pack K-chunk-major with bank swizzle baked in:
// element k of row r -> tile k/64, byte (k&63) ^ ((r&7)<<3).
// Grid: 2 mats x 128 rows x 4 slabs = 1024 blocks.
__global__ __launch_bounds__(256, 4) void k_pack(
    const float* __restrict__ A, const float* __restrict__ B,
    char* __restrict__ packA, char* __restrict__ packB,
    float* __restrict__ sqBuf, int base, int cnt)
{
    const int bid = blockIdx.x;
    const int mat  = bid >> 9;
    const int r    = (bid >> 2) & 127;
    const int slab = bid & 3;
    const int t    = threadIdx.x;

    const float4* s4 = (const float4*)((mat ? B : A) + (size_t)r * DFEAT
                                       + (size_t)base * 64);
    char* pk = (mat ? packB : packA) + (size_t)r * 64;
    const int PS = cnt * 4;            // float4s per slab (cnt*16 total /4 slabs)
    const int i0 = slab * PS;
    const unsigned sw = (unsigned)((r & 7) << 3);

    float sq = 0.f;
    for (int i = t; i < PS; i += 256) {
        int f4 = i0 + i;
        float4 v = s4[f4];
        sq += v.x*v.x + v.y*v.y + v.z*v.z + v.w*v.w;
        int k  = f4 << 2;
        int lc = k >> 6;
        unsigned j = (unsigned)(k & 63) ^ sw;
        *(unsigned*)(pk + (size_t)lc * TILE_B + j) = fp8x4(v);
    }
    __shared__ float ws[4];
    #pragma unroll
    for (int m = 32; m >= 1; m >>= 1) sq += __shfl_xor(sq, m);
    if ((t & 63) == 0) ws[t >> 6] = sq;
    __syncthreads();
    if (t == 0) atomicAdd(&sqBuf[mat * 128 + r], ws[0] + ws[1] + ws[2] + ws[3]);
}

// Pass 2: 128x128 Gram from packed fp8. Each block owns a CONTIGUOUS run of
// tiles; quad-buffered global_load_lds (1KB contiguous per instr), counted
// vmcnt(2); fp8 MFMA; diagonal-collapse epilogue.
__global__ __launch_bounds__(1024, 1) void k_gram(
    const char* __restrict__ packA, const char* __restrict__ packB,
    float* __restrict__ diag, int cnt)
{
    __shared__ alignas(16) char lds[65536];   // 4 bufs x (A 8K | B 8K)

    const int t = threadIdx.x, g = blockIdx.x;
    const int w = t >> 6, l = t & 63;
    const int wrow = w >> 2, wcol = w & 3;    // 4x4 waves, 32x32 out each
    const int fr = l & 15, grp = l >> 4;

    f32x4 acc00 = {0,0,0,0}, acc01 = {0,0,0,0},
          acc10 = {0,0,0,0}, acc11 = {0,0,0,0};

    // staging: waves 0-7 stage the A tile, 8-15 the B tile (1KB per instr)
    const char* stSrc = (w < 8) ? packA : packB;
    const int   stOff = (w & 7) * 1024 + l * 16;
    const int   stLds = ((w < 8) ? 0 : 8192) + (w & 7) * 1024;

    const int tstart = (g * cnt) >> 8;        // contiguous tile range
    const int tend   = ((g + 1) * cnt) >> 8;
    const int nt     = tend - tstart;

#define ISSUE(K) do {                                                   \
    int kk_ = (K); if (kk_ > nt - 1) kk_ = nt - 1;                      \
    gload16(stSrc + (size_t)(tstart + kk_) * TILE_B + stOff,            \
            &lds[(((K) & 3) << 14) + stLds]);                           \
} while (0)

    if (nt > 0) {
        ISSUE(0); ISSUE(1); ISSUE(2);
        for (int k = 0; k < nt; k++) {
            asm volatile("s_waitcnt vmcnt(2)" ::: "memory");  // tile k landed
            __builtin_amdgcn_s_barrier();
            __builtin_amdgcn_sched_barrier(0);

            const int pb = (k & 3) << 14;
            const int m0 = wrow * 32 + fr, m1 = m0 + 16;
            const int n0 = wcol * 32 + fr, n1 = n0 + 16;
            const int sa = (m0 & 7) << 3;
            const int sb = (n0 & 7) << 3;
            #pragma unroll
            for (int ks = 0; ks < 2; ks++) {
                int j = ks * 32 + grp * 8;
                long long a0 = *(const long long*)&lds[pb + m0 * 64 + (j ^ sa)];
                long long a1 = *(const long long*)&lds[pb + m1 * 64 + (j ^ sa)];
                long long b0 = *(const long long*)&lds[pb + 8192 + n0 * 64 + (j ^ sb)];
                long long b1 = *(const long long*)&lds[pb + 8192 + n1 * 64 + (j ^ sb)];
                acc00 = __builtin_amdgcn_mfma_f32_16x16x32_fp8_fp8(a0, b0, acc00, 0, 0, 0);
                acc01 = __builtin_amdgcn_mfma_f32_16x16x32_fp8_fp8(a0, b1, acc01, 0, 0, 0);
                acc10 = __builtin_amdgcn_mfma_f32_16x16x32_fp8_fp8(a1, b0, acc10, 0, 0, 0);
                acc11 = __builtin_amdgcn_mfma_f32_16x16x32_fp8_fp8(a1, b1, acc11, 0, 0, 0);
            }
            ISSUE(k + 3);                           // into buf (k-1)&3: safe
            asm volatile("s_waitcnt lgkmcnt(0)" ::: "memory");
            __builtin_amdgcn_sched_barrier(0);
            __builtin_amdgcn_s_barrier();           // reads done; buf recyclable
        }
    }
#undef ISSUE

    // drain outstanding direct-to-LDS writes before repurposing LDS
    asm volatile("s_waitcnt vmcnt(0)" ::: "memory");
    __syncthreads();

    // ---- epilogue: two 64-row halves through padded LDS, stride 129 ----
    // C/D layout: col = lane&15, row = (lane>>4)*4 + reg
    float* ldsF = (float*)lds;                  // [64][129] = 33KB
    float dsum = 0.f;
    const int del = t - 127;
    const int crow = grp * 4, ccol = fr;
    for (int h = 0; h < 2; h++) {
        if (h) __syncthreads();
        if ((wrow >> 1) == h) {
            #pragma unroll
            for (int tm = 0; tm < 2; tm++)
                #pragma unroll
                for (int tn = 0; tn < 2; tn++) {
                    f32x4 av = (tm == 0) ? (tn == 0 ? acc00 : acc01)
                                         : (tn == 0 ? acc10 : acc11);
                    int row0 = wrow * 32 + tm * 16 + crow - h * 64;
                    int col  = wcol * 32 + tn * 16 + ccol;
                    #pragma unroll
                    for (int rg = 0; rg < 4; rg++)
                        ldsF[(row0 + rg) * 129 + col] = av[rg];
                }
        }
        __syncthreads();
        if (t < 255) {
            int rlo = del < 0 ? -del : 0;
            int rhi = del < 0 ? 127 : 127 - del;   // inclusive
            if (rlo < h * 64) rlo = h * 64;
            if (rhi > h * 64 + 63) rhi = h * 64 + 63;
            for (int r = rlo; r <= rhi; r++)
                dsum += ldsF[(r - h * 64) * 129 + r + del];
        }
    }
    if (t < 255) atomicAdd(&diag[t], dsum);
}

// K3: prefix-sum the norms, combine with diagonal gram sums -> 129 outputs.
__global__ void k3_out(const float* __restrict__ sqBuf,
                       const float* __restrict__ diag,
                       float* __restrict__ out)
{
    __shared__ float sa[128], sb[128], psA[129], psB[129];
    int t = threadIdx.x;
    if (t < 128) sa[t] = sqBuf[t];
    else if (t < 256) sb[t - 128] = sqBuf[t];
    __syncthreads();
    if (t == 0) { float s = 0; psA[0] = 0; for (int i = 0; i < 128; i++) { s += sa[i]; psA[i+1] = s; } }
    if (t == 1) { float s = 0; psB[0] = 0; for (int i = 0; i < 128; i++) { s += sb[i]; psB[i+1] = s; } }
    __syncthreads();
    if (t < 129) {
        int d = t - 64;
        int ad = d < 0 ? -d : d;
        int cntt = 128 - ad;
        int i0 = d < 0 ? -d : 0;
        float sq = (psA[i0 + cntt] - psA[i0]) + (psB[i0 + d + cntt] - psB[i0 + d]);
        float gv = diag[63 + t];
        out[t] = -((sq - 2.f * gv) / (float)DFEAT) * 1e13f / (float)cntt;
    }
}

extern "C" void kernel_launch(void* const* d_in, const int* in_sizes, int n_in,
                              void* d_out, int out_size, void* d_ws, size_t ws_size,
                              hipStream_t stream) {
    const float* clip1 = (const float*)d_in[0];  // b: matrix cols (y)
    const float* clip2 = (const float*)d_in[1];  // a: matrix rows (x)
    float* out = (float*)d_out;

    float* sqBuf = (float*)d_ws;                 // 256 f
    float* diag  = sqBuf + 256;                  // 255 f

    size_t avail = ws_size > 4096 ? ws_size - 4096 : 0;
    long maxtiles = (long)(avail / (2 * (size_t)TILE_B));
    int cnt = (int)(maxtiles < NC_TOT ? maxtiles : NC_TOT);
    if (cnt < 1) cnt = 1;
    int R = (NC_TOT + cnt - 1) / cnt;

    char* packA = (char*)d_ws + 4096;
    char* packB = packA + (size_t)cnt * TILE_B;

    hipMemsetAsync(d_ws, 0, 4096, stream);
    for (int rd = 0; rd < R; rd++) {
        int b0 = rd * cnt;
        int cR = (NC_TOT - b0 < cnt) ? (NC_TOT - b0) : cnt;
        k_pack<<<dim3(1024), dim3(256), 0, stream>>>(clip2, clip1, packA, packB,
                                                     sqBuf, b0, cR);
        k_gram<<<dim3(256), dim3(1024), 0, stream>>>(packA, packB, diag, cR);
    }
    k3_out<<<dim3(1), dim3(256), 0, stream>>>(sqBuf, diag, out);
}